// Round 1
// baseline (412.317 us; speedup 1.0000x reference)
//
#include <hip/hip_runtime.h>

// ---------------------------------------------------------------------------
// UFO linear attention: qkv = x@Wqkv; kv = k^T v per head; xnorm(kv), xnorm(q);
// out = q_n @ kv_n; final = out @ W_o + b_o.
// B=4, N=4096, DIM=1024, H=16, Dh=64.  All big matmuls in bf16 MFMA.
// ---------------------------------------------------------------------------

typedef __bf16 bf16;
typedef bf16  bf16x8 __attribute__((ext_vector_type(8)));
typedef bf16  bf16x4 __attribute__((ext_vector_type(4)));
typedef float f32x4  __attribute__((ext_vector_type(4)));

#define BATCH   4
#define SEQ     4096
#define DIM     1024
#define HEADS   16
#define DHEAD   64
#define MTOK    (BATCH*SEQ)          // 16384
#define N_QKV   (3*DIM)              // 3072
#define NSPLIT  16                   // kv einsum n-splits

typedef __attribute__((address_space(1))) const void gas_v;
typedef __attribute__((address_space(3))) void las_v;

__device__ __forceinline__ void gld_lds16(const void* g, void* l) {
  // async global->LDS, 16B per lane; LDS dest must be wave-uniform base + lane*16
  __builtin_amdgcn_global_load_lds((gas_v*)g, (las_v*)l, 16, 0, 0);
}

// ---------------------------------------------------------------------------
// K1a: pack x (fp32) -> bf16, 8 elems/thread
// ---------------------------------------------------------------------------
__global__ __launch_bounds__(256) void pack_x(const float* __restrict__ x,
                                              bf16* __restrict__ xb) {
  size_t i = (size_t)blockIdx.x * 256 + threadIdx.x;   // 2,097,152 threads
  f32x4 a = *(const f32x4*)&x[i * 8];
  f32x4 b = *(const f32x4*)&x[i * 8 + 4];
  bf16x8 o = {(bf16)a.x, (bf16)a.y, (bf16)a.z, (bf16)a.w,
              (bf16)b.x, (bf16)b.y, (bf16)b.z, (bf16)b.w};
  *(bf16x8*)&xb[i * 8] = o;
}

// ---------------------------------------------------------------------------
// K1b/c: transpose fp32 [R][C] -> bf16 [C][R]  (32x32 LDS tiles, +1 pad)
// ---------------------------------------------------------------------------
__global__ __launch_bounds__(256) void transpose_bf16(const float* __restrict__ in,
                                                      bf16* __restrict__ out,
                                                      int R, int C) {
  __shared__ float tile[32][33];
  int c0 = blockIdx.x * 32, r0 = blockIdx.y * 32;
  int tx = threadIdx.x, ty = threadIdx.y;     // block (32, 8)
#pragma unroll
  for (int i = 0; i < 32; i += 8)
    tile[ty + i][tx] = in[(size_t)(r0 + ty + i) * C + c0 + tx];
  __syncthreads();
#pragma unroll
  for (int i = 0; i < 32; i += 8)
    out[(size_t)(c0 + ty + i) * R + r0 + tx] = (bf16)tile[tx][ty + i];
}

// ---------------------------------------------------------------------------
// GEMM  C[M,N] = A[M,K] * Bt[N,K]^T   (bf16 in, fp32 acc). m97 structure:
// 128x128 tile, BK=32, global_load_lds w16, XOR-swizzled LDS chunks.
// MODE 1: split epilogue q(fp32)/k(bf16)/v(bf16).   MODE 2: +bias, fp32 out.
// ---------------------------------------------------------------------------
template <int MODE>
__global__ __launch_bounds__(256) void gemm_bt(
    const bf16* __restrict__ A, const bf16* __restrict__ Bt, int N, int K,
    float* __restrict__ C, const float* __restrict__ bias,
    float* __restrict__ qf, bf16* __restrict__ kb, bf16* __restrict__ vb) {
  __shared__ bf16 lA[128 * 32];   // 8 KB, rows of 32 bf16 (4 chunks of 16B)
  __shared__ bf16 lB[128 * 32];
  const int t    = threadIdx.x;
  const int lane = t & 63;
  const int wv   = t >> 6;
  const int m0   = blockIdx.y * 128;
  const int n0   = blockIdx.x * 128;
  const int wm   = (wv >> 1) * 64;
  const int wn   = (wv & 1) * 64;
  const int lr   = lane & 15;     // row within 16x16 tile
  const int ks   = lane >> 4;     // k-chunk (8 elems) for this quad

  f32x4 acc[4][4];
#pragma unroll
  for (int i = 0; i < 4; i++)
#pragma unroll
    for (int j = 0; j < 4; j++) acc[i][j] = {0.f, 0.f, 0.f, 0.f};

  // fragment LDS offsets (swizzle x(row) = (row>>1)&3 on 16B chunks)
  int aoff[4], boff[4];
#pragma unroll
  for (int i = 0; i < 4; i++) {
    int ra  = wm + i * 16 + lr;
    aoff[i] = ra * 32 + ((ks ^ ((ra >> 1) & 3)) * 8);
    int rb  = wn + i * 16 + lr;
    boff[i] = rb * 32 + ((ks ^ ((rb >> 1) & 3)) * 8);
  }
  const int srow = t >> 2;        // staging row (+64 for phase 1)
  const int sseg = t & 3;         // staging 16B chunk within row

  for (int k0 = 0; k0 < K; k0 += 32) {
#pragma unroll
    for (int p = 0; p < 2; p++) {
      int row  = p * 64 + srow;
      int gseg = sseg ^ ((row >> 1) & 3);
      gld_lds16(A + (size_t)(m0 + row) * K + k0 + gseg * 8,
                &lA[row * 32 + sseg * 8]);
      gld_lds16(Bt + (size_t)(n0 + row) * K + k0 + gseg * 8,
                &lB[row * 32 + sseg * 8]);
    }
    __syncthreads();
    bf16x8 af[4], bfv[4];
#pragma unroll
    for (int i = 0; i < 4; i++) af[i] = *(const bf16x8*)&lA[aoff[i]];
#pragma unroll
    for (int j = 0; j < 4; j++) bfv[j] = *(const bf16x8*)&lB[boff[j]];
#pragma unroll
    for (int i = 0; i < 4; i++)
#pragma unroll
      for (int j = 0; j < 4; j++)
        acc[i][j] = __builtin_amdgcn_mfma_f32_16x16x32_bf16(af[i], bfv[j],
                                                            acc[i][j], 0, 0, 0);
    __syncthreads();
  }

  // epilogue: C layout col=lane&15, row=(lane>>4)*4+reg  (m89-verified)
  const int crow0 = m0 + wm + (lane >> 4) * 4;
  const int ccol0 = n0 + wn + lr;
#pragma unroll
  for (int i = 0; i < 4; i++)
#pragma unroll
    for (int j = 0; j < 4; j++) {
      int col = ccol0 + j * 16;
#pragma unroll
      for (int r = 0; r < 4; r++) {
        int row  = crow0 + i * 16 + r;
        float v  = acc[i][j][r];
        if (MODE == 2) {
          C[(size_t)row * N + col] = v + bias[col];
        } else {
          if (col < DIM)            qf[(size_t)row * DIM + col] = v;
          else if (col < 2 * DIM)   kb[(size_t)row * DIM + (col - DIM)] = (bf16)v;
          else                      vb[(size_t)row * DIM + (col - 2 * DIM)] = (bf16)v;
        }
      }
    }
}

// ---------------------------------------------------------------------------
// K3: kv partials. grid (NSPLIT, 64bh). kv[d][e] += sum_n k[n,d]*v[n,e]
// fp32 outer-product, 4x4 acc/thread, LDS-staged bf16->fp32 tiles.
// ---------------------------------------------------------------------------
__global__ __launch_bounds__(256) void kv_partial(const bf16* __restrict__ kb,
                                                  const bf16* __restrict__ vb,
                                                  float* __restrict__ part) {
  __shared__ float lK[32 * 64];   // 8 KB
  __shared__ float lV[32 * 64];
  const int t  = threadIdx.x;
  const int s  = blockIdx.x;      // n-split
  const int bh = blockIdx.y;
  const int b  = bh >> 4, h = bh & 15;
  const size_t base = ((size_t)b * SEQ + s * (SEQ / NSPLIT)) * DIM + h * DHEAD;
  const int d0 = (t & 15) * 4, e0 = (t >> 4) * 4;
  const int rr = t >> 3, cc = (t & 7) * 8;   // staging: row, col-chunk

  float acc[4][4];
#pragma unroll
  for (int a = 0; a < 4; a++)
#pragma unroll
    for (int q = 0; q < 4; q++) acc[a][q] = 0.f;

  for (int nt = 0; nt < (SEQ / NSPLIT) / 32; nt++) {
    size_t g = base + (size_t)(nt * 32 + rr) * DIM + cc;
    bf16x8 k8 = *(const bf16x8*)(kb + g);
    bf16x8 v8 = *(const bf16x8*)(vb + g);
    f32x4 klo = {(float)k8[0], (float)k8[1], (float)k8[2], (float)k8[3]};
    f32x4 khi = {(float)k8[4], (float)k8[5], (float)k8[6], (float)k8[7]};
    f32x4 vlo = {(float)v8[0], (float)v8[1], (float)v8[2], (float)v8[3]};
    f32x4 vhi = {(float)v8[4], (float)v8[5], (float)v8[6], (float)v8[7]};
    *(f32x4*)&lK[rr * 64 + cc]     = klo;
    *(f32x4*)&lK[rr * 64 + cc + 4] = khi;
    *(f32x4*)&lV[rr * 64 + cc]     = vlo;
    *(f32x4*)&lV[rr * 64 + cc + 4] = vhi;
    __syncthreads();
#pragma unroll 8
    for (int nn = 0; nn < 32; nn++) {
      f32x4 kk = *(const f32x4*)&lK[nn * 64 + d0];
      f32x4 vv = *(const f32x4*)&lV[nn * 64 + e0];
#pragma unroll
      for (int a = 0; a < 4; a++)
#pragma unroll
        for (int q = 0; q < 4; q++) acc[a][q] += kk[a] * vv[q];
    }
    __syncthreads();
  }
  float* pb = part + ((size_t)bh * NSPLIT + s) * 4096;
#pragma unroll
  for (int a = 0; a < 4; a++) {
    f32x4 o = {acc[a][0], acc[a][1], acc[a][2], acc[a][3]};
    *(f32x4*)&pb[(d0 + a) * 64 + e0] = o;
  }
}

// ---------------------------------------------------------------------------
// K3b: reduce partials, row-norm over e, scale by gamma/norm, write kvnT bf16
// (transposed: kvnT[bh][e][d] so it is the Bt operand of out-GEMM)
// ---------------------------------------------------------------------------
__global__ __launch_bounds__(256) void kv_norm(const float* __restrict__ part,
                                               const float* __restrict__ gamma,
                                               bf16* __restrict__ kvnT) {
  const int t  = threadIdx.x;
  const int bh = blockIdx.x;
  const int h  = bh & 15;
  const int d  = t >> 2;
  const int eq = (t & 3) * 16;
  float v[16];
#pragma unroll
  for (int j = 0; j < 16; j++) v[j] = 0.f;
  for (int s = 0; s < NSPLIT; s++) {
    const float* p = part + ((size_t)bh * NSPLIT + s) * 4096 + d * 64 + eq;
#pragma unroll
    for (int j4 = 0; j4 < 4; j4++) {
      f32x4 a = *(const f32x4*)&p[j4 * 4];
      v[j4 * 4 + 0] += a.x; v[j4 * 4 + 1] += a.y;
      v[j4 * 4 + 2] += a.z; v[j4 * 4 + 3] += a.w;
    }
  }
  float ss = 0.f;
#pragma unroll
  for (int j = 0; j < 16; j++) ss += v[j] * v[j];
  ss += __shfl_xor(ss, 1);
  ss += __shfl_xor(ss, 2);            // 4 lanes share d
  float scale = gamma[h] * rsqrtf(ss);
#pragma unroll
  for (int j = 0; j < 16; j++)
    kvnT[(size_t)bh * 4096 + (eq + j) * 64 + d] = (bf16)(v[j] * scale);
}

// ---------------------------------------------------------------------------
// K4: q_n = q * gamma / ||q||  per (token, head). 16-lane groups, coalesced.
// ---------------------------------------------------------------------------
__global__ __launch_bounds__(256) void qnorm(const float* __restrict__ qf,
                                             const float* __restrict__ gamma,
                                             bf16* __restrict__ qn) {
  int g = blockIdx.x * 256 + threadIdx.x;      // 4,194,304 threads, 4 elems each
  f32x4 x4 = *(const f32x4*)&qf[(size_t)g * 4];
  float ss = x4.x * x4.x + x4.y * x4.y + x4.z * x4.z + x4.w * x4.w;
  ss += __shfl_xor(ss, 1);
  ss += __shfl_xor(ss, 2);
  ss += __shfl_xor(ss, 4);
  ss += __shfl_xor(ss, 8);                     // 16 lanes = one head-segment
  int h = (g >> 4) & 15;
  float sc = gamma[h] * rsqrtf(ss);
  bf16x4 o = {(bf16)(x4.x * sc), (bf16)(x4.y * sc),
              (bf16)(x4.z * sc), (bf16)(x4.w * sc)};
  *(bf16x4*)&qn[(size_t)g * 4] = o;
}

// ---------------------------------------------------------------------------
// K5: out[n,e] = sum_d qn[n,d] * kvn[d,e]  per (b,h). MFMA, tile 128x64, K=64.
// grid (SEQ/128, 64bh). Writes bf16 out in [token][h*64+e] layout (GEMM2's A).
// ---------------------------------------------------------------------------
__global__ __launch_bounds__(256) void out_gemm(const bf16* __restrict__ qn,
                                                const bf16* __restrict__ kvnT,
                                                bf16* __restrict__ outb) {
  __shared__ bf16 lA[128 * 64];   // 16 KB, rows of 64 bf16 (8 chunks of 16B)
  __shared__ bf16 lB[64 * 64];    // 8 KB
  const int t    = threadIdx.x;
  const int lane = t & 63;
  const int wv   = t >> 6;
  const int bh   = blockIdx.y;
  const int b    = bh >> 4, h = bh & 15;
  const int n0   = blockIdx.x * 128;
  const size_t qbase = ((size_t)b * SEQ + n0) * DIM + h * DHEAD;
  const size_t kvb   = (size_t)bh * 4096;

#pragma unroll
  for (int p = 0; p < 4; p++) {            // A: 1024 chunks of 16B
    int c = p * 256 + t;
    int row = c >> 3, seg = c & 7;
    int gsk = seg ^ (row & 7);
    gld_lds16(qn + qbase + (size_t)row * DIM + gsk * 8, &lA[row * 64 + seg * 8]);
  }
#pragma unroll
  for (int p = 0; p < 2; p++) {            // B: 512 chunks
    int c = p * 256 + t;
    int row = c >> 3, seg = c & 7;
    int gsk = seg ^ (row & 7);
    gld_lds16(kvnT + kvb + row * 64 + gsk * 8, &lB[row * 64 + seg * 8]);
  }
  __syncthreads();

  const int lr = lane & 15, ks = lane >> 4;
  f32x4 acc[2][4];
#pragma unroll
  for (int i = 0; i < 2; i++)
#pragma unroll
    for (int j = 0; j < 4; j++) acc[i][j] = {0.f, 0.f, 0.f, 0.f};

#pragma unroll
  for (int kk = 0; kk < 2; kk++) {         // k0 = kk*32
    bf16x8 af[2], bfv[4];
#pragma unroll
    for (int i = 0; i < 2; i++) {
      int row = wv * 32 + i * 16 + lr;
      int seg = (kk * 4 + ks) ^ (row & 7);
      af[i] = *(const bf16x8*)&lA[row * 64 + seg * 8];
    }
#pragma unroll
    for (int j = 0; j < 4; j++) {
      int row = j * 16 + lr;
      int seg = (kk * 4 + ks) ^ (row & 7);
      bfv[j] = *(const bf16x8*)&lB[row * 64 + seg * 8];
    }
#pragma unroll
    for (int i = 0; i < 2; i++)
#pragma unroll
      for (int j = 0; j < 4; j++)
        acc[i][j] = __builtin_amdgcn_mfma_f32_16x16x32_bf16(af[i], bfv[j],
                                                            acc[i][j], 0, 0, 0);
  }

  const size_t obase = qbase;              // same [token][h*64+e] layout
#pragma unroll
  for (int i = 0; i < 2; i++)
#pragma unroll
    for (int j = 0; j < 4; j++) {
      int col = j * 16 + lr;
#pragma unroll
      for (int r = 0; r < 4; r++) {
        int row = wv * 32 + i * 16 + (lane >> 4) * 4 + r;
        outb[obase + (size_t)row * DIM + col] = (bf16)acc[i][j][r];
      }
    }
}

// ---------------------------------------------------------------------------
extern "C" void kernel_launch(void* const* d_in, const int* in_sizes, int n_in,
                              void* d_out, int out_size, void* d_ws,
                              size_t ws_size, hipStream_t stream) {
  const float* x     = (const float*)d_in[0];
  const float* Wqkv  = (const float*)d_in[1];
  const float* Wo    = (const float*)d_in[2];
  const float* bo    = (const float*)d_in[3];
  const float* gamma = (const float*)d_in[4];
  float* out = (float*)d_out;

  char* ws = (char*)d_ws;
  size_t off = 0;
  bf16*  xb   = (bf16*)(ws + off);  off += (size_t)MTOK * DIM * 2;        // 32 MB
  bf16*  WqT  = (bf16*)(ws + off);  off += (size_t)N_QKV * DIM * 2;       //  6 MB
  bf16*  WoT  = (bf16*)(ws + off);  off += (size_t)DIM * DIM * 2;         //  2 MB
  bf16*  kvnT = (bf16*)(ws + off);  off += (size_t)64 * 4096 * 2;         // .5 MB
  float* qf   = (float*)(ws + off);                                        // 64 MB
  bf16*  outb = (bf16*)(ws + off);  off += (size_t)MTOK * DIM * 4;        // outb aliases qf (dead after qnorm)
  bf16*  kb   = (bf16*)(ws + off);  off += (size_t)MTOK * DIM * 2;        // 32 MB
  bf16*  vb   = (bf16*)(ws + off);  off += (size_t)MTOK * DIM * 2;        // 32 MB
  float* part = (float*)(ws + off); off += (size_t)64 * NSPLIT * 4096 * 4;// 16 MB
  bf16*  qn   = (bf16*)(ws + off);  off += (size_t)MTOK * DIM * 2;        // 32 MB

  pack_x<<<dim3(MTOK * DIM / (8 * 256)), dim3(256), 0, stream>>>(x, xb);
  transpose_bf16<<<dim3(N_QKV / 32, DIM / 32), dim3(32, 8), 0, stream>>>(
      Wqkv, WqT, DIM, N_QKV);
  transpose_bf16<<<dim3(DIM / 32, DIM / 32), dim3(32, 8), 0, stream>>>(
      Wo, WoT, DIM, DIM);

  gemm_bt<1><<<dim3(N_QKV / 128, MTOK / 128), dim3(256), 0, stream>>>(
      xb, WqT, N_QKV, DIM, nullptr, nullptr, qf, kb, vb);

  kv_partial<<<dim3(NSPLIT, 64), dim3(256), 0, stream>>>(kb, vb, part);
  kv_norm<<<dim3(64), dim3(256), 0, stream>>>(part, gamma, kvnT);
  qnorm<<<dim3(MTOK * DIM / (4 * 256)), dim3(256), 0, stream>>>(qf, gamma, qn);
  out_gemm<<<dim3(SEQ / 128, 64), dim3(256), 0, stream>>>(qn, kvnT, outb);

  gemm_bt<2><<<dim3(DIM / 128, MTOK / 128), dim3(256), 0, stream>>>(
      outb, WoT, DIM, DIM, out, bo, nullptr, nullptr, nullptr);
}

// Round 3
// 376.989 us; speedup vs baseline: 1.0937x; 1.0937x over previous
//
#include <hip/hip_runtime.h>

// ---------------------------------------------------------------------------
// UFO linear attention: qkv = x@Wqkv; kv = k^T v per head; xnorm(kv), xnorm(q);
// out = q_n @ kv_n; final = out @ W_o + b_o.
// B=4, N=4096, DIM=1024, H=16, Dh=64.  All big matmuls in bf16 MFMA.
// R2: q-norm fused into GEMM1 epilogue (wave's 64 cols == one head);
//     block-uniform q/k/v epilogue dispatch; kv_norm 4x more blocks.
// R3: fix MODE-2 launch arity (pass gamma=nullptr).
// ---------------------------------------------------------------------------

typedef __bf16 bf16;
typedef bf16  bf16x8 __attribute__((ext_vector_type(8)));
typedef bf16  bf16x4 __attribute__((ext_vector_type(4)));
typedef float f32x4  __attribute__((ext_vector_type(4)));

#define BATCH   4
#define SEQ     4096
#define DIM     1024
#define HEADS   16
#define DHEAD   64
#define MTOK    (BATCH*SEQ)          // 16384
#define N_QKV   (3*DIM)              // 3072
#define NSPLIT  16                   // kv einsum n-splits

typedef __attribute__((address_space(1))) const void gas_v;
typedef __attribute__((address_space(3))) void las_v;

__device__ __forceinline__ void gld_lds16(const void* g, void* l) {
  // async global->LDS, 16B per lane; LDS dest must be wave-uniform base + lane*16
  __builtin_amdgcn_global_load_lds((gas_v*)g, (las_v*)l, 16, 0, 0);
}

// ---------------------------------------------------------------------------
// K1a: pack x (fp32) -> bf16, 8 elems/thread
// ---------------------------------------------------------------------------
__global__ __launch_bounds__(256) void pack_x(const float* __restrict__ x,
                                              bf16* __restrict__ xb) {
  size_t i = (size_t)blockIdx.x * 256 + threadIdx.x;   // 2,097,152 threads
  f32x4 a = *(const f32x4*)&x[i * 8];
  f32x4 b = *(const f32x4*)&x[i * 8 + 4];
  bf16x8 o = {(bf16)a.x, (bf16)a.y, (bf16)a.z, (bf16)a.w,
              (bf16)b.x, (bf16)b.y, (bf16)b.z, (bf16)b.w};
  *(bf16x8*)&xb[i * 8] = o;
}

// ---------------------------------------------------------------------------
// K1b/c: transpose fp32 [R][C] -> bf16 [C][R]  (32x32 LDS tiles, +1 pad)
// ---------------------------------------------------------------------------
__global__ __launch_bounds__(256) void transpose_bf16(const float* __restrict__ in,
                                                      bf16* __restrict__ out,
                                                      int R, int C) {
  __shared__ float tile[32][33];
  int c0 = blockIdx.x * 32, r0 = blockIdx.y * 32;
  int tx = threadIdx.x, ty = threadIdx.y;     // block (32, 8)
#pragma unroll
  for (int i = 0; i < 32; i += 8)
    tile[ty + i][tx] = in[(size_t)(r0 + ty + i) * C + c0 + tx];
  __syncthreads();
#pragma unroll
  for (int i = 0; i < 32; i += 8)
    out[(size_t)(c0 + ty + i) * R + r0 + tx] = (bf16)tile[tx][ty + i];
}

// ---------------------------------------------------------------------------
// GEMM  C[M,N] = A[M,K] * Bt[N,K]^T   (bf16 in, fp32 acc). m97 structure:
// 128x128 tile, BK=32, global_load_lds w16, XOR-swizzled LDS chunks.
// MODE 1: block-uniform epilogue: q -> fused xnorm -> bf16 qn; k,v -> bf16.
// MODE 2: +bias, fp32 out.
// ---------------------------------------------------------------------------
template <int MODE>
__global__ __launch_bounds__(256) void gemm_bt(
    const bf16* __restrict__ A, const bf16* __restrict__ Bt, int N, int K,
    float* __restrict__ C, const float* __restrict__ bias,
    const float* __restrict__ gamma,
    bf16* __restrict__ qn, bf16* __restrict__ kb, bf16* __restrict__ vb) {
  __shared__ bf16 lA[128 * 32];   // 8 KB, rows of 32 bf16 (4 chunks of 16B)
  __shared__ bf16 lB[128 * 32];
  const int t    = threadIdx.x;
  const int lane = t & 63;
  const int wv   = t >> 6;
  const int m0   = blockIdx.y * 128;
  const int n0   = blockIdx.x * 128;
  const int wm   = (wv >> 1) * 64;
  const int wn   = (wv & 1) * 64;
  const int lr   = lane & 15;     // row within 16x16 tile
  const int ks   = lane >> 4;     // k-chunk (8 elems) for this quad

  f32x4 acc[4][4];
#pragma unroll
  for (int i = 0; i < 4; i++)
#pragma unroll
    for (int j = 0; j < 4; j++) acc[i][j] = {0.f, 0.f, 0.f, 0.f};

  // fragment LDS offsets (swizzle x(row) = (row>>1)&3 on 16B chunks)
  int aoff[4], boff[4];
#pragma unroll
  for (int i = 0; i < 4; i++) {
    int ra  = wm + i * 16 + lr;
    aoff[i] = ra * 32 + ((ks ^ ((ra >> 1) & 3)) * 8);
    int rb  = wn + i * 16 + lr;
    boff[i] = rb * 32 + ((ks ^ ((rb >> 1) & 3)) * 8);
  }
  const int srow = t >> 2;        // staging row (+64 for phase 1)
  const int sseg = t & 3;         // staging 16B chunk within row

  for (int k0 = 0; k0 < K; k0 += 32) {
#pragma unroll
    for (int p = 0; p < 2; p++) {
      int row  = p * 64 + srow;
      int gseg = sseg ^ ((row >> 1) & 3);
      gld_lds16(A + (size_t)(m0 + row) * K + k0 + gseg * 8,
                &lA[row * 32 + sseg * 8]);
      gld_lds16(Bt + (size_t)(n0 + row) * K + k0 + gseg * 8,
                &lB[row * 32 + sseg * 8]);
    }
    __syncthreads();
    bf16x8 af[4], bfv[4];
#pragma unroll
    for (int i = 0; i < 4; i++) af[i] = *(const bf16x8*)&lA[aoff[i]];
#pragma unroll
    for (int j = 0; j < 4; j++) bfv[j] = *(const bf16x8*)&lB[boff[j]];
#pragma unroll
    for (int i = 0; i < 4; i++)
#pragma unroll
      for (int j = 0; j < 4; j++)
        acc[i][j] = __builtin_amdgcn_mfma_f32_16x16x32_bf16(af[i], bfv[j],
                                                            acc[i][j], 0, 0, 0);
    __syncthreads();
  }

  // epilogue: C layout col=lane&15, row=(lane>>4)*4+reg  (m89-verified)
  const int crow0 = m0 + wm + (lane >> 4) * 4;

  if (MODE == 2) {
    const int ccol0 = n0 + wn + lr;
#pragma unroll
    for (int i = 0; i < 4; i++)
#pragma unroll
      for (int j = 0; j < 4; j++) {
        int col = ccol0 + j * 16;
#pragma unroll
        for (int r = 0; r < 4; r++)
          C[(size_t)(crow0 + i * 16 + r) * N + col] = acc[i][j][r] + bias[col];
      }
  } else {
    const int seg = n0 >> 10;           // block-uniform: 0=q, 1=k, 2=v
    if (seg == 0) {
      // fused q-norm: this wave's 64 cols are exactly head h
      const int h   = (n0 + wn) >> 6;
      const float g = gamma[h];
      const int col0 = n0 + wn + lr;    // global col == qn col (head-major)
#pragma unroll
      for (int i = 0; i < 4; i++)
#pragma unroll
        for (int r = 0; r < 4; r++) {
          float p = acc[i][0][r] * acc[i][0][r] + acc[i][1][r] * acc[i][1][r]
                  + acc[i][2][r] * acc[i][2][r] + acc[i][3][r] * acc[i][3][r];
          p += __shfl_xor(p, 1);
          p += __shfl_xor(p, 2);
          p += __shfl_xor(p, 4);
          p += __shfl_xor(p, 8);        // 16 lanes = the head's 64 cols
          float sc = g * rsqrtf(p);
          size_t rb = (size_t)(crow0 + i * 16 + r) * DIM + col0;
#pragma unroll
          for (int j = 0; j < 4; j++)
            qn[rb + j * 16] = (bf16)(acc[i][j][r] * sc);
        }
    } else {
      bf16* dst = (seg == 1) ? kb : vb;
      const int ccol0 = (n0 - seg * DIM) + wn + lr;
#pragma unroll
      for (int i = 0; i < 4; i++)
#pragma unroll
        for (int j = 0; j < 4; j++) {
          int col = ccol0 + j * 16;
#pragma unroll
          for (int r = 0; r < 4; r++)
            dst[(size_t)(crow0 + i * 16 + r) * DIM + col] = (bf16)acc[i][j][r];
        }
    }
  }
}

// ---------------------------------------------------------------------------
// K3: kv partials. grid (NSPLIT, 64bh). kv[d][e] += sum_n k[n,d]*v[n,e]
// fp32 outer-product, 4x4 acc/thread, LDS-staged bf16->fp32 tiles.
// ---------------------------------------------------------------------------
__global__ __launch_bounds__(256) void kv_partial(const bf16* __restrict__ kb,
                                                  const bf16* __restrict__ vb,
                                                  float* __restrict__ part) {
  __shared__ float lK[32 * 64];   // 8 KB
  __shared__ float lV[32 * 64];
  const int t  = threadIdx.x;
  const int s  = blockIdx.x;      // n-split
  const int bh = blockIdx.y;
  const int b  = bh >> 4, h = bh & 15;
  const size_t base = ((size_t)b * SEQ + s * (SEQ / NSPLIT)) * DIM + h * DHEAD;
  const int d0 = (t & 15) * 4, e0 = (t >> 4) * 4;
  const int rr = t >> 3, cc = (t & 7) * 8;   // staging: row, col-chunk

  float acc[4][4];
#pragma unroll
  for (int a = 0; a < 4; a++)
#pragma unroll
    for (int q = 0; q < 4; q++) acc[a][q] = 0.f;

  for (int nt = 0; nt < (SEQ / NSPLIT) / 32; nt++) {
    size_t g = base + (size_t)(nt * 32 + rr) * DIM + cc;
    bf16x8 k8 = *(const bf16x8*)(kb + g);
    bf16x8 v8 = *(const bf16x8*)(vb + g);
    f32x4 klo = {(float)k8[0], (float)k8[1], (float)k8[2], (float)k8[3]};
    f32x4 khi = {(float)k8[4], (float)k8[5], (float)k8[6], (float)k8[7]};
    f32x4 vlo = {(float)v8[0], (float)v8[1], (float)v8[2], (float)v8[3]};
    f32x4 vhi = {(float)v8[4], (float)v8[5], (float)v8[6], (float)v8[7]};
    *(f32x4*)&lK[rr * 64 + cc]     = klo;
    *(f32x4*)&lK[rr * 64 + cc + 4] = khi;
    *(f32x4*)&lV[rr * 64 + cc]     = vlo;
    *(f32x4*)&lV[rr * 64 + cc + 4] = vhi;
    __syncthreads();
#pragma unroll 8
    for (int nn = 0; nn < 32; nn++) {
      f32x4 kk = *(const f32x4*)&lK[nn * 64 + d0];
      f32x4 vv = *(const f32x4*)&lV[nn * 64 + e0];
#pragma unroll
      for (int a = 0; a < 4; a++)
#pragma unroll
        for (int q = 0; q < 4; q++) acc[a][q] += kk[a] * vv[q];
    }
    __syncthreads();
  }
  float* pb = part + ((size_t)bh * NSPLIT + s) * 4096;
#pragma unroll
  for (int a = 0; a < 4; a++) {
    f32x4 o = {acc[a][0], acc[a][1], acc[a][2], acc[a][3]};
    *(f32x4*)&pb[(d0 + a) * 64 + e0] = o;
  }
}

// ---------------------------------------------------------------------------
// K3b: reduce partials, row-norm over e, scale by gamma/norm, write kvnT bf16
// (transposed: kvnT[bh][e][d] = Bt operand of out-GEMM). grid 256: (bh, d/16)
// ---------------------------------------------------------------------------
__global__ __launch_bounds__(256) void kv_norm(const float* __restrict__ part,
                                               const float* __restrict__ gamma,
                                               bf16* __restrict__ kvnT) {
  const int t   = threadIdx.x;
  const int bh  = blockIdx.x >> 2;
  const int h   = bh & 15;
  const int d   = (blockIdx.x & 3) * 16 + (t >> 4);
  const int e0  = (t & 15) * 4;
  f32x4 v = {0.f, 0.f, 0.f, 0.f};
  for (int s = 0; s < NSPLIT; s++) {
    f32x4 a = *(const f32x4*)(part + ((size_t)bh * NSPLIT + s) * 4096 + d * 64 + e0);
    v.x += a.x; v.y += a.y; v.z += a.z; v.w += a.w;
  }
  float ss = v.x * v.x + v.y * v.y + v.z * v.z + v.w * v.w;
  ss += __shfl_xor(ss, 1);
  ss += __shfl_xor(ss, 2);
  ss += __shfl_xor(ss, 4);
  ss += __shfl_xor(ss, 8);          // 16 consecutive lanes share d
  float scale = gamma[h] * rsqrtf(ss);
#pragma unroll
  for (int j = 0; j < 4; j++)
    kvnT[(size_t)bh * 4096 + (e0 + j) * 64 + d] = (bf16)(v[j] * scale);
}

// ---------------------------------------------------------------------------
// K5: out[n,e] = sum_d qn[n,d] * kvn[d,e]  per (b,h). MFMA, tile 128x64, K=64.
// grid (SEQ/128, 64bh). Writes bf16 out in [token][h*64+e] layout (GEMM2's A).
// ---------------------------------------------------------------------------
__global__ __launch_bounds__(256) void out_gemm(const bf16* __restrict__ qn,
                                                const bf16* __restrict__ kvnT,
                                                bf16* __restrict__ outb) {
  __shared__ bf16 lA[128 * 64];   // 16 KB, rows of 64 bf16 (8 chunks of 16B)
  __shared__ bf16 lB[64 * 64];    // 8 KB
  const int t    = threadIdx.x;
  const int lane = t & 63;
  const int wv   = t >> 6;
  const int bh   = blockIdx.y;
  const int b    = bh >> 4, h = bh & 15;
  const int n0   = blockIdx.x * 128;
  const size_t qbase = ((size_t)b * SEQ + n0) * DIM + h * DHEAD;
  const size_t kvb   = (size_t)bh * 4096;

#pragma unroll
  for (int p = 0; p < 4; p++) {            // A: 1024 chunks of 16B
    int c = p * 256 + t;
    int row = c >> 3, seg = c & 7;
    int gsk = seg ^ (row & 7);
    gld_lds16(qn + qbase + (size_t)row * DIM + gsk * 8, &lA[row * 64 + seg * 8]);
  }
#pragma unroll
  for (int p = 0; p < 2; p++) {            // B: 512 chunks
    int c = p * 256 + t;
    int row = c >> 3, seg = c & 7;
    int gsk = seg ^ (row & 7);
    gld_lds16(kvnT + kvb + row * 64 + gsk * 8, &lB[row * 64 + seg * 8]);
  }
  __syncthreads();

  const int lr = lane & 15, ks = lane >> 4;
  f32x4 acc[2][4];
#pragma unroll
  for (int i = 0; i < 2; i++)
#pragma unroll
    for (int j = 0; j < 4; j++) acc[i][j] = {0.f, 0.f, 0.f, 0.f};

#pragma unroll
  for (int kk = 0; kk < 2; kk++) {         // k0 = kk*32
    bf16x8 af[2], bfv[4];
#pragma unroll
    for (int i = 0; i < 2; i++) {
      int row = wv * 32 + i * 16 + lr;
      int seg = (kk * 4 + ks) ^ (row & 7);
      af[i] = *(const bf16x8*)&lA[row * 64 + seg * 8];
    }
#pragma unroll
    for (int j = 0; j < 4; j++) {
      int row = j * 16 + lr;
      int seg = (kk * 4 + ks) ^ (row & 7);
      bfv[j] = *(const bf16x8*)&lB[row * 64 + seg * 8];
    }
#pragma unroll
    for (int i = 0; i < 2; i++)
#pragma unroll
      for (int j = 0; j < 4; j++)
        acc[i][j] = __builtin_amdgcn_mfma_f32_16x16x32_bf16(af[i], bfv[j],
                                                            acc[i][j], 0, 0, 0);
  }

  const size_t obase = qbase;              // same [token][h*64+e] layout
#pragma unroll
  for (int i = 0; i < 2; i++)
#pragma unroll
    for (int j = 0; j < 4; j++) {
      int col = j * 16 + lr;
#pragma unroll
      for (int r = 0; r < 4; r++) {
        int row = wv * 32 + i * 16 + (lane >> 4) * 4 + r;
        outb[obase + (size_t)row * DIM + col] = (bf16)acc[i][j][r];
      }
    }
}

// ---------------------------------------------------------------------------
extern "C" void kernel_launch(void* const* d_in, const int* in_sizes, int n_in,
                              void* d_out, int out_size, void* d_ws,
                              size_t ws_size, hipStream_t stream) {
  const float* x     = (const float*)d_in[0];
  const float* Wqkv  = (const float*)d_in[1];
  const float* Wo    = (const float*)d_in[2];
  const float* bo    = (const float*)d_in[3];
  const float* gamma = (const float*)d_in[4];
  float* out = (float*)d_out;

  char* ws = (char*)d_ws;
  size_t off = 0;
  bf16*  xb   = (bf16*)(ws + off);  off += (size_t)MTOK * DIM * 2;        // 32 MB
  bf16*  WqT  = (bf16*)(ws + off);  off += (size_t)N_QKV * DIM * 2;       //  6 MB
  bf16*  WoT  = (bf16*)(ws + off);  off += (size_t)DIM * DIM * 2;         //  2 MB
  bf16*  kvnT = (bf16*)(ws + off);  off += (size_t)64 * 4096 * 2;         // .5 MB
  bf16*  qn   = (bf16*)(ws + off);  off += (size_t)MTOK * DIM * 2;        // 32 MB
  bf16*  kb   = (bf16*)(ws + off);  off += (size_t)MTOK * DIM * 2;        // 32 MB
  bf16*  vb   = (bf16*)(ws + off);  off += (size_t)MTOK * DIM * 2;        // 32 MB
  float* part = (float*)(ws + off); off += (size_t)64 * NSPLIT * 4096 * 4;// 16 MB
  bf16*  outb = (bf16*)(ws + off);  off += (size_t)MTOK * DIM * 2;        // 32 MB

  pack_x<<<dim3(MTOK * DIM / (8 * 256)), dim3(256), 0, stream>>>(x, xb);
  transpose_bf16<<<dim3(N_QKV / 32, DIM / 32), dim3(32, 8), 0, stream>>>(
      Wqkv, WqT, DIM, N_QKV);
  transpose_bf16<<<dim3(DIM / 32, DIM / 32), dim3(32, 8), 0, stream>>>(
      Wo, WoT, DIM, DIM);

  gemm_bt<1><<<dim3(N_QKV / 128, MTOK / 128), dim3(256), 0, stream>>>(
      xb, WqT, N_QKV, DIM, nullptr, nullptr, gamma, qn, kb, vb);

  kv_partial<<<dim3(NSPLIT, 64), dim3(256), 0, stream>>>(kb, vb, part);
  kv_norm<<<dim3(256), dim3(256), 0, stream>>>(part, gamma, kvnT);
  out_gemm<<<dim3(SEQ / 128, 64), dim3(256), 0, stream>>>(qn, kvnT, outb);

  gemm_bt<2><<<dim3(DIM / 128, MTOK / 128), dim3(256), 0, stream>>>(
      outb, WoT, DIM, DIM, out, bo, nullptr, nullptr, nullptr, nullptr);
}